// Round 2
// baseline (360.923 us; speedup 1.0000x reference)
//
#include <hip/hip_runtime.h>
#include <math.h>

// DecomposedFrequencyLearning: NaN-fill -> rfft(4096) -> 4x freq mask -> irfft
// x[32,4096,64] f32  ->  out[4,32,4096,64] f32
//
// One WG per (batch, channel-pair); 2 real channels packed as 1 complex FFT
// (real symmetric mask commutes with the Hermitian split).
// Register-blocked radix-4^2 phases: 16 pts/thread, 2 radix-4 stages per LDS
// exchange. Forward: P1(stride256)->P2(block16)->P3(contig). Inverse mirrors.
// All LDS exchange patterns are bank-uniform under pad(v)=v+(v>>4).

namespace {

constexpr int NFFT = 4096;
constexpr int NT   = 256;
constexpr int NB   = 32;
constexpr int NC   = 64;
constexpr int KF   = 4;

__device__ __forceinline__ int pad(int i) { return i + (i >> 4); }

__device__ __forceinline__ float2 cadd(float2 a, float2 b){ return make_float2(a.x+b.x, a.y+b.y); }
__device__ __forceinline__ float2 csub(float2 a, float2 b){ return make_float2(a.x-b.x, a.y-b.y); }
__device__ __forceinline__ float2 cmul(float2 a, float2 b){
    return make_float2(fmaf(a.x,b.x,-(a.y*b.y)), fmaf(a.x,b.y, a.y*b.x));
}
// a * conj(b)
__device__ __forceinline__ float2 cmulc(float2 a, float2 b){
    return make_float2(fmaf(a.x,b.x, a.y*b.y), fmaf(a.y,b.x,-(a.x*b.y)));
}

__device__ __forceinline__ void bf4_fwd(float2&a,float2&b,float2&c,float2&d){
    float2 t0=cadd(a,c), t1=csub(a,c), t2=cadd(b,d), t3=csub(b,d);
    float2 mi3=make_float2(t3.y,-t3.x);          // -i*t3
    a=cadd(t0,t2); b=cadd(t1,mi3); c=csub(t0,t2); d=csub(t1,mi3);
}
__device__ __forceinline__ void bf4_inv(float2&a,float2&b,float2&c,float2&d){
    float2 t0=cadd(a,c), t1=csub(a,c), t2=cadd(b,d), t3=csub(b,d);
    float2 pi3=make_float2(-t3.y,t3.x);          // +i*t3
    a=cadd(t0,t2); b=cadd(t1,pi3); c=csub(t0,t2); d=csub(t1,pi3);
}
// DIF: butterfly then twiddle outputs 1..3
__device__ __forceinline__ void grp_fwd(float2&a,float2&b,float2&c,float2&d,
                                        float2 w1, float2 w2, float2 w3){
    bf4_fwd(a,b,c,d);
    b=cmul(b,w1); c=cmul(c,w2); d=cmul(d,w3);
}
__device__ __forceinline__ void xgrp_fwd(float2&a,float2&b,float2&c,float2&d, float2 w1){
    float2 w2=cmul(w1,w1), w3=cmul(w2,w1);
    grp_fwd(a,b,c,d,w1,w2,w3);
}
// DIT: conj-twiddle inputs 1..3 then butterfly
__device__ __forceinline__ void grp_inv(float2&a,float2&b,float2&c,float2&d,
                                        float2 w1, float2 w2, float2 w3){
    b=cmulc(b,w1); c=cmulc(c,w2); d=cmulc(d,w3);
    bf4_inv(a,b,c,d);
}
__device__ __forceinline__ void xgrp_inv(float2&a,float2&b,float2&c,float2&d, float2 w1){
    float2 w2=cmul(w1,w1), w3=cmul(w2,w1);
    grp_inv(a,b,c,d,w1,w2,w3);
}

__global__ __launch_bounds__(NT, 4)
void dfl_kernel(const float* __restrict__ x,
                const int* __restrict__ taus,
                const int* __restrict__ mus,
                float* __restrict__ out)
{
    __shared__ float2 buf[NFFT + NFFT/16];   // 4352*8 = 34816 B (padded)
    __shared__ float2 wtab[512];             // 4096 B ; total 38912 B -> 4 WG/CU

    const int tid = threadIdx.x;
    // XCD-chunked swizzle: blocks sharing a batch land on one XCD.
    const int l  = ((blockIdx.x & 7) << 7) | (blockIdx.x >> 3);
    const int b  = l >> 5;
    const int c0 = (l & 31) << 1;
    const float QNAN = __uint_as_float(0x7fc00000u);

    // w(j) = exp(-2*pi*i*j/4096), j<512
    for (int j = tid; j < 512; j += NT) {
        float s, c; sincosf(-3.14159265358979f * (float)j / 2048.0f, &s, &c);
        wtab[j] = make_float2(c, s);
    }

    float2* chLast  = buf;        // [256] scratch, overwritten later
    float2* chFirst = buf + 256;  // [256]

    // ---- load + in-chunk forward fill (thread t owns times [16t,16t+16)) ----
    const float* xb = x + ((size_t)b * NFFT) * NC + c0;
    float2 z[16];
    float2 last = make_float2(QNAN, QNAN), first = make_float2(QNAN, QNAN);
    #pragma unroll
    for (int j = 0; j < 16; ++j) {
        float2 v = *reinterpret_cast<const float2*>(xb + (size_t)(16*tid + j) * NC);
        if (first.x != first.x && v.x == v.x) first.x = v.x;
        if (first.y != first.y && v.y == v.y) first.y = v.y;
        if (v.x == v.x) last.x = v.x; else v.x = last.x;
        if (v.y == v.y) last.y = v.y; else v.y = last.y;
        z[j] = v;                               // NaN only in leading run
    }
    chLast[tid] = last;
    chFirst[tid] = first;
    __syncthreads();                            // S1

    // last observed before this chunk
    float2 pre = make_float2(QNAN, QNAN);
    for (int k = tid - 1; k >= 0; --k) {
        float2 s2 = chLast[k];
        if (pre.x != pre.x) pre.x = s2.x;
        if (pre.y != pre.y) pre.y = s2.y;
        if (pre.x == pre.x && pre.y == pre.y) break;
    }
    // globally first observed (backward-fill value for the leading prefix)
    float2 gfirst = make_float2(QNAN, QNAN);
    for (int k = 0; k < NT; ++k) {
        float2 s2 = chFirst[k];
        if (gfirst.x != gfirst.x) gfirst.x = s2.x;
        if (gfirst.y != gfirst.y) gfirst.y = s2.y;
        if (gfirst.x == gfirst.x && gfirst.y == gfirst.y) break;
    }
    if (gfirst.x != gfirst.x) gfirst.x = 0.f;   // all-NaN -> 0
    if (gfirst.y != gfirst.y) gfirst.y = 0.f;
    const float fx = (pre.x == pre.x) ? pre.x : gfirst.x;
    const float fy = (pre.y == pre.y) ? pre.y : gfirst.y;
    #pragma unroll
    for (int j = 0; j < 16; ++j) {
        if (z[j].x != z[j].x) z[j].x = fx;
        if (z[j].y != z[j].y) z[j].y = fy;
    }

    // ---- per-thread twiddle bases (one-time) ----
    const float2 wm = wtab[tid];                        // w(m)
    float2 q2 = cmul(wm, wm);
    const float2 w4m = cmul(q2, q2);                    // w(4m)
    const float2 w16r = wtab[16 * (tid & 15)];          // w(16r)
    float2 q3 = cmul(w16r, w16r);
    const float2 w64r = cmul(q3, q3);                   // w(64r)

    const float2 W1 = make_float2( 0.92387953251f,-0.38268343236f); // w(256)
    const float2 W2 = make_float2( 0.70710678119f,-0.70710678119f); // w(512)
    const float2 W3 = make_float2( 0.38268343236f,-0.92387953251f); // w(768)
    const float2 W4 = make_float2( 0.f,-1.f);                       // w(1024)
    const float2 W6 = make_float2(-0.70710678119f,-0.70710678119f); // w(1536)
    const float2 W9 = make_float2(-0.92387953251f, 0.38268343236f); // w(2304)

    __syncthreads();                            // S2: scans done, buf reusable

    // ---- write x_clean at P3 (natural time) ----
    #pragma unroll
    for (int j = 0; j < 16; ++j) buf[pad(16*tid + j)] = z[j];
    __syncthreads();                            // S3

    // ================= forward DIF =================
    // phase A on P1 (n = m + 256j)
    #pragma unroll
    for (int j = 0; j < 16; ++j) z[j] = buf[pad(tid + 256*j)];
    // stage0: X-groups, k1 = m + 256*jp
    xgrp_fwd(z[0],z[4],z[8],z[12], wm);
    xgrp_fwd(z[1],z[5],z[9],z[13], cmul(wm,W1));
    xgrp_fwd(z[2],z[6],z[10],z[14], cmul(wm,W2));
    xgrp_fwd(z[3],z[7],z[11],z[15], cmul(wm,W3));
    // stage1: Y-groups, k1 = 4m (same for all groups)
    {   float2 w1=w4m, w2=cmul(w1,w1), w3=cmul(w2,w1);
        grp_fwd(z[0],z[1],z[2],z[3],  w1,w2,w3);
        grp_fwd(z[4],z[5],z[6],z[7],  w1,w2,w3);
        grp_fwd(z[8],z[9],z[10],z[11],w1,w2,w3);
        grp_fwd(z[12],z[13],z[14],z[15],w1,w2,w3);
    }
    #pragma unroll
    for (int j = 0; j < 16; ++j) buf[pad(tid + 256*j)] = z[j];
    __syncthreads();                            // S4

    // phase B on P2 (n = (m>>4)*256 + (m&15) + 16j)
    const int p2b = ((tid >> 4) << 8) + (tid & 15);
    #pragma unroll
    for (int j = 0; j < 16; ++j) z[j] = buf[pad(p2b + 16*j)];
    // stage2: X-groups, k1 = 16r + 256*jp
    xgrp_fwd(z[0],z[4],z[8],z[12], w16r);
    xgrp_fwd(z[1],z[5],z[9],z[13], cmul(w16r,W1));
    xgrp_fwd(z[2],z[6],z[10],z[14], cmul(w16r,W2));
    xgrp_fwd(z[3],z[7],z[11],z[15], cmul(w16r,W3));
    // stage3: Y-groups, k1 = 64r
    {   float2 w1=w64r, w2=cmul(w1,w1), w3=cmul(w2,w1);
        grp_fwd(z[0],z[1],z[2],z[3],  w1,w2,w3);
        grp_fwd(z[4],z[5],z[6],z[7],  w1,w2,w3);
        grp_fwd(z[8],z[9],z[10],z[11],w1,w2,w3);
        grp_fwd(z[12],z[13],z[14],z[15],w1,w2,w3);
    }
    #pragma unroll
    for (int j = 0; j < 16; ++j) buf[pad(p2b + 16*j)] = z[j];
    __syncthreads();                            // S5

    // phase C on P3 (n = 16m + j)
    #pragma unroll
    for (int j = 0; j < 16; ++j) z[j] = buf[pad(16*tid + j)];
    // stage4: X-groups, k1 = 256*jp (constants)
    bf4_fwd(z[0],z[4],z[8],z[12]);
    grp_fwd(z[1],z[5],z[9],z[13], W1,W2,W3);
    grp_fwd(z[2],z[6],z[10],z[14], W2,W4,W6);
    grp_fwd(z[3],z[7],z[11],z[15], W3,W6,W9);
    // stage5: Y-groups, no twiddle
    bf4_fwd(z[0],z[1],z[2],z[3]);
    bf4_fwd(z[4],z[5],z[6],z[7]);
    bf4_fwd(z[8],z[9],z[10],z[11]);
    bf4_fwd(z[12],z[13],z[14],z[15]);

    // park spectrum (position n = 16m+j, frequency = digitrev4(n))
    float2 spec[16];
    #pragma unroll
    for (int j = 0; j < 16; ++j) spec[j] = z[j];

    // digit-reverse of tid (4 base-4 digits)
    const int revtid = ((tid & 3) << 6) | (((tid >> 2) & 3) << 4)
                     | (((tid >> 4) & 3) << 2) | (tid >> 6);

    const float scale = 1.0f / (float)NFFT;

    // ================= per-filter inverse DIT =================
    #pragma unroll 1
    for (int k = 0; k < KF; ++k) {
        const int tau = taus[k];
        const int mu  = mus[k];
        __syncthreads();                        // prior reads of buf complete

        // mask in regs (P3 positions)
        #pragma unroll
        for (int j = 0; j < 16; ++j) {
            const int r = revtid + ((j & 3) << 10) + ((j >> 2) << 8);
            const int f = (r <= 2048) ? r : (NFFT - r);
            const bool keep = (mu == 1) ? (f < tau) : (f >= tau);
            z[j] = keep ? spec[j] : make_float2(0.f, 0.f);
        }
        // stage0: Y-groups, no twiddle
        bf4_inv(z[0],z[1],z[2],z[3]);
        bf4_inv(z[4],z[5],z[6],z[7]);
        bf4_inv(z[8],z[9],z[10],z[11]);
        bf4_inv(z[12],z[13],z[14],z[15]);
        // stage1: X-groups, k1 = 256*jp (constants)
        bf4_inv(z[0],z[4],z[8],z[12]);
        grp_inv(z[1],z[5],z[9],z[13], W1,W2,W3);
        grp_inv(z[2],z[6],z[10],z[14], W2,W4,W6);
        grp_inv(z[3],z[7],z[11],z[15], W3,W6,W9);
        #pragma unroll
        for (int j = 0; j < 16; ++j) buf[pad(16*tid + j)] = z[j];
        __syncthreads();

        #pragma unroll
        for (int j = 0; j < 16; ++j) z[j] = buf[pad(p2b + 16*j)];
        // stage2: Y-groups, k1 = 64r
        {   float2 w1=w64r, w2=cmul(w1,w1), w3=cmul(w2,w1);
            grp_inv(z[0],z[1],z[2],z[3],  w1,w2,w3);
            grp_inv(z[4],z[5],z[6],z[7],  w1,w2,w3);
            grp_inv(z[8],z[9],z[10],z[11],w1,w2,w3);
            grp_inv(z[12],z[13],z[14],z[15],w1,w2,w3);
        }
        // stage3: X-groups, k1 = 16r + 256*jp
        xgrp_inv(z[0],z[4],z[8],z[12], w16r);
        xgrp_inv(z[1],z[5],z[9],z[13], cmul(w16r,W1));
        xgrp_inv(z[2],z[6],z[10],z[14], cmul(w16r,W2));
        xgrp_inv(z[3],z[7],z[11],z[15], cmul(w16r,W3));
        #pragma unroll
        for (int j = 0; j < 16; ++j) buf[pad(p2b + 16*j)] = z[j];
        __syncthreads();

        #pragma unroll
        for (int j = 0; j < 16; ++j) z[j] = buf[pad(tid + 256*j)];
        // stage4: Y-groups, k1 = 4m
        {   float2 w1=w4m, w2=cmul(w1,w1), w3=cmul(w2,w1);
            grp_inv(z[0],z[1],z[2],z[3],  w1,w2,w3);
            grp_inv(z[4],z[5],z[6],z[7],  w1,w2,w3);
            grp_inv(z[8],z[9],z[10],z[11],w1,w2,w3);
            grp_inv(z[12],z[13],z[14],z[15],w1,w2,w3);
        }
        // stage5: X-groups, k1 = m + 256*jp
        xgrp_inv(z[0],z[4],z[8],z[12], wm);
        xgrp_inv(z[1],z[5],z[9],z[13], cmul(wm,W1));
        xgrp_inv(z[2],z[6],z[10],z[14], cmul(wm,W2));
        xgrp_inv(z[3],z[7],z[11],z[15], cmul(wm,W3));

        // store natural order: thread m owns t = m + 256j
        float* ob = out + ((size_t)(k*NB + b) * NFFT) * NC + c0;
        #pragma unroll
        for (int j = 0; j < 16; ++j) {
            const int t = tid + 256*j;
            *reinterpret_cast<float2*>(ob + (size_t)t * NC) =
                make_float2(z[j].x * scale, z[j].y * scale);
        }
    }
}

} // namespace

extern "C" void kernel_launch(void* const* d_in, const int* in_sizes, int n_in,
                              void* d_out, int out_size, void* d_ws, size_t ws_size,
                              hipStream_t stream) {
    (void)in_sizes; (void)n_in; (void)out_size; (void)d_ws; (void)ws_size;
    const float* x  = (const float*)d_in[0];
    const int* taus = (const int*)d_in[1];
    const int* mus  = (const int*)d_in[2];
    float* out      = (float*)d_out;
    dfl_kernel<<<dim3(NB * NC / 2), dim3(NT), 0, stream>>>(x, taus, mus, out);
}

// Round 3
// 116.609 us; speedup vs baseline: 3.0952x; 3.0952x over previous
//
#include <hip/hip_runtime.h>
#include <math.h>

// DecomposedFrequencyLearning: NaN-fill -> rfft(4096) -> 4x freq mask -> irfft
// x[32,4096,64] f32  ->  out[4,32,4096,64] f32
//
// One WG per (batch, channel-pair); 2 real channels packed as 1 complex FFT
// (real symmetric mask commutes with the Hermitian split).
// Register-blocked radix-4^2 phases: 16 pts/thread, 2 radix-4 stages per LDS
// exchange. Forward: P1(stride256)->P2(block16)->P3(contig). Inverse mirrors.
// All LDS exchange patterns are bank-uniform under pad(v)=v+(v>>4).
//
// R3: __launch_bounds__(256) WITHOUT a min-wave clamp. R2's (256,4) capped
// VGPRs at 128 and spilled z[16]+spec[16] to scratch (FETCH 394MB, WRITE
// 800MB, VALUBusy 7%). ~110 VGPRs still gives 4 WG/CU (LDS-limited too).

namespace {

constexpr int NFFT = 4096;
constexpr int NT   = 256;
constexpr int NB   = 32;
constexpr int NC   = 64;
constexpr int KF   = 4;

__device__ __forceinline__ int pad(int i) { return i + (i >> 4); }

__device__ __forceinline__ float2 cadd(float2 a, float2 b){ return make_float2(a.x+b.x, a.y+b.y); }
__device__ __forceinline__ float2 csub(float2 a, float2 b){ return make_float2(a.x-b.x, a.y-b.y); }
__device__ __forceinline__ float2 cmul(float2 a, float2 b){
    return make_float2(fmaf(a.x,b.x,-(a.y*b.y)), fmaf(a.x,b.y, a.y*b.x));
}
// a * conj(b)
__device__ __forceinline__ float2 cmulc(float2 a, float2 b){
    return make_float2(fmaf(a.x,b.x, a.y*b.y), fmaf(a.y,b.x,-(a.x*b.y)));
}

__device__ __forceinline__ void bf4_fwd(float2&a,float2&b,float2&c,float2&d){
    float2 t0=cadd(a,c), t1=csub(a,c), t2=cadd(b,d), t3=csub(b,d);
    float2 mi3=make_float2(t3.y,-t3.x);          // -i*t3
    a=cadd(t0,t2); b=cadd(t1,mi3); c=csub(t0,t2); d=csub(t1,mi3);
}
__device__ __forceinline__ void bf4_inv(float2&a,float2&b,float2&c,float2&d){
    float2 t0=cadd(a,c), t1=csub(a,c), t2=cadd(b,d), t3=csub(b,d);
    float2 pi3=make_float2(-t3.y,t3.x);          // +i*t3
    a=cadd(t0,t2); b=cadd(t1,pi3); c=csub(t0,t2); d=csub(t1,pi3);
}
// DIF: butterfly then twiddle outputs 1..3
__device__ __forceinline__ void grp_fwd(float2&a,float2&b,float2&c,float2&d,
                                        float2 w1, float2 w2, float2 w3){
    bf4_fwd(a,b,c,d);
    b=cmul(b,w1); c=cmul(c,w2); d=cmul(d,w3);
}
__device__ __forceinline__ void xgrp_fwd(float2&a,float2&b,float2&c,float2&d, float2 w1){
    float2 w2=cmul(w1,w1), w3=cmul(w2,w1);
    grp_fwd(a,b,c,d,w1,w2,w3);
}
// DIT: conj-twiddle inputs 1..3 then butterfly
__device__ __forceinline__ void grp_inv(float2&a,float2&b,float2&c,float2&d,
                                        float2 w1, float2 w2, float2 w3){
    b=cmulc(b,w1); c=cmulc(c,w2); d=cmulc(d,w3);
    bf4_inv(a,b,c,d);
}
__device__ __forceinline__ void xgrp_inv(float2&a,float2&b,float2&c,float2&d, float2 w1){
    float2 w2=cmul(w1,w1), w3=cmul(w2,w1);
    grp_inv(a,b,c,d,w1,w2,w3);
}

__global__ __launch_bounds__(NT)
void dfl_kernel(const float* __restrict__ x,
                const int* __restrict__ taus,
                const int* __restrict__ mus,
                float* __restrict__ out)
{
    __shared__ float2 buf[NFFT + NFFT/16];   // 4352*8 = 34816 B (padded)
    __shared__ float2 wtab[512];             // 4096 B ; total 38912 B -> 4 WG/CU

    const int tid = threadIdx.x;
    // XCD-chunked swizzle: blocks sharing a batch land on one XCD.
    const int l  = ((blockIdx.x & 7) << 7) | (blockIdx.x >> 3);
    const int b  = l >> 5;
    const int c0 = (l & 31) << 1;
    const float QNAN = __uint_as_float(0x7fc00000u);

    // w(j) = exp(-2*pi*i*j/4096), j<512
    for (int j = tid; j < 512; j += NT) {
        float s, c; sincosf(-3.14159265358979f * (float)j / 2048.0f, &s, &c);
        wtab[j] = make_float2(c, s);
    }

    float2* chLast  = buf;        // [256] scratch, overwritten later
    float2* chFirst = buf + 256;  // [256]

    // ---- load + in-chunk forward fill (thread t owns times [16t,16t+16)) ----
    const float* xb = x + ((size_t)b * NFFT) * NC + c0;
    float2 z[16];
    float2 last = make_float2(QNAN, QNAN), first = make_float2(QNAN, QNAN);
    #pragma unroll
    for (int j = 0; j < 16; ++j) {
        float2 v = *reinterpret_cast<const float2*>(xb + (size_t)(16*tid + j) * NC);
        if (first.x != first.x && v.x == v.x) first.x = v.x;
        if (first.y != first.y && v.y == v.y) first.y = v.y;
        if (v.x == v.x) last.x = v.x; else v.x = last.x;
        if (v.y == v.y) last.y = v.y; else v.y = last.y;
        z[j] = v;                               // NaN only in leading run
    }
    chLast[tid] = last;
    chFirst[tid] = first;
    __syncthreads();                            // S1

    // last observed before this chunk
    float2 pre = make_float2(QNAN, QNAN);
    for (int k = tid - 1; k >= 0; --k) {
        float2 s2 = chLast[k];
        if (pre.x != pre.x) pre.x = s2.x;
        if (pre.y != pre.y) pre.y = s2.y;
        if (pre.x == pre.x && pre.y == pre.y) break;
    }
    // globally first observed (backward-fill value for the leading prefix)
    float2 gfirst = make_float2(QNAN, QNAN);
    for (int k = 0; k < NT; ++k) {
        float2 s2 = chFirst[k];
        if (gfirst.x != gfirst.x) gfirst.x = s2.x;
        if (gfirst.y != gfirst.y) gfirst.y = s2.y;
        if (gfirst.x == gfirst.x && gfirst.y == gfirst.y) break;
    }
    if (gfirst.x != gfirst.x) gfirst.x = 0.f;   // all-NaN -> 0
    if (gfirst.y != gfirst.y) gfirst.y = 0.f;
    const float fx = (pre.x == pre.x) ? pre.x : gfirst.x;
    const float fy = (pre.y == pre.y) ? pre.y : gfirst.y;
    #pragma unroll
    for (int j = 0; j < 16; ++j) {
        if (z[j].x != z[j].x) z[j].x = fx;
        if (z[j].y != z[j].y) z[j].y = fy;
    }

    // ---- per-thread twiddle bases (one-time) ----
    const float2 wm = wtab[tid];                        // w(m)
    float2 q2 = cmul(wm, wm);
    const float2 w4m = cmul(q2, q2);                    // w(4m)
    const float2 w16r = wtab[16 * (tid & 15)];          // w(16r)
    float2 q3 = cmul(w16r, w16r);
    const float2 w64r = cmul(q3, q3);                   // w(64r)

    const float2 W1 = make_float2( 0.92387953251f,-0.38268343236f); // w(256)
    const float2 W2 = make_float2( 0.70710678119f,-0.70710678119f); // w(512)
    const float2 W3 = make_float2( 0.38268343236f,-0.92387953251f); // w(768)
    const float2 W4 = make_float2( 0.f,-1.f);                       // w(1024)
    const float2 W6 = make_float2(-0.70710678119f,-0.70710678119f); // w(1536)
    const float2 W9 = make_float2(-0.92387953251f, 0.38268343236f); // w(2304)

    __syncthreads();                            // S2: scans done, buf reusable

    // ---- write x_clean at P3 (natural time) ----
    #pragma unroll
    for (int j = 0; j < 16; ++j) buf[pad(16*tid + j)] = z[j];
    __syncthreads();                            // S3

    // ================= forward DIF =================
    // phase A on P1 (n = m + 256j)
    #pragma unroll
    for (int j = 0; j < 16; ++j) z[j] = buf[pad(tid + 256*j)];
    // stage0: X-groups, k1 = m + 256*jp
    xgrp_fwd(z[0],z[4],z[8],z[12], wm);
    xgrp_fwd(z[1],z[5],z[9],z[13], cmul(wm,W1));
    xgrp_fwd(z[2],z[6],z[10],z[14], cmul(wm,W2));
    xgrp_fwd(z[3],z[7],z[11],z[15], cmul(wm,W3));
    // stage1: Y-groups, k1 = 4m (same for all groups)
    {   float2 w1=w4m, w2=cmul(w1,w1), w3=cmul(w2,w1);
        grp_fwd(z[0],z[1],z[2],z[3],  w1,w2,w3);
        grp_fwd(z[4],z[5],z[6],z[7],  w1,w2,w3);
        grp_fwd(z[8],z[9],z[10],z[11],w1,w2,w3);
        grp_fwd(z[12],z[13],z[14],z[15],w1,w2,w3);
    }
    #pragma unroll
    for (int j = 0; j < 16; ++j) buf[pad(tid + 256*j)] = z[j];
    __syncthreads();                            // S4

    // phase B on P2 (n = (m>>4)*256 + (m&15) + 16j)
    const int p2b = ((tid >> 4) << 8) + (tid & 15);
    #pragma unroll
    for (int j = 0; j < 16; ++j) z[j] = buf[pad(p2b + 16*j)];
    // stage2: X-groups, k1 = 16r + 256*jp
    xgrp_fwd(z[0],z[4],z[8],z[12], w16r);
    xgrp_fwd(z[1],z[5],z[9],z[13], cmul(w16r,W1));
    xgrp_fwd(z[2],z[6],z[10],z[14], cmul(w16r,W2));
    xgrp_fwd(z[3],z[7],z[11],z[15], cmul(w16r,W3));
    // stage3: Y-groups, k1 = 64r
    {   float2 w1=w64r, w2=cmul(w1,w1), w3=cmul(w2,w1);
        grp_fwd(z[0],z[1],z[2],z[3],  w1,w2,w3);
        grp_fwd(z[4],z[5],z[6],z[7],  w1,w2,w3);
        grp_fwd(z[8],z[9],z[10],z[11],w1,w2,w3);
        grp_fwd(z[12],z[13],z[14],z[15],w1,w2,w3);
    }
    #pragma unroll
    for (int j = 0; j < 16; ++j) buf[pad(p2b + 16*j)] = z[j];
    __syncthreads();                            // S5

    // phase C on P3 (n = 16m + j)
    #pragma unroll
    for (int j = 0; j < 16; ++j) z[j] = buf[pad(16*tid + j)];
    // stage4: X-groups, k1 = 256*jp (constants)
    bf4_fwd(z[0],z[4],z[8],z[12]);
    grp_fwd(z[1],z[5],z[9],z[13], W1,W2,W3);
    grp_fwd(z[2],z[6],z[10],z[14], W2,W4,W6);
    grp_fwd(z[3],z[7],z[11],z[15], W3,W6,W9);
    // stage5: Y-groups, no twiddle
    bf4_fwd(z[0],z[1],z[2],z[3]);
    bf4_fwd(z[4],z[5],z[6],z[7]);
    bf4_fwd(z[8],z[9],z[10],z[11]);
    bf4_fwd(z[12],z[13],z[14],z[15]);

    // park spectrum scaled by 1/N (linear; mask is a selection so this
    // commutes with everything downstream). Position n = 16m+j.
    const float scale = 1.0f / (float)NFFT;
    float2 spec[16];
    #pragma unroll
    for (int j = 0; j < 16; ++j)
        spec[j] = make_float2(z[j].x * scale, z[j].y * scale);

    // digit-reverse of tid (4 base-4 digits)
    const int revtid = ((tid & 3) << 6) | (((tid >> 2) & 3) << 4)
                     | (((tid >> 4) & 3) << 2) | (tid >> 6);

    // ================= per-filter inverse DIT =================
    #pragma unroll 1
    for (int k = 0; k < KF; ++k) {
        const int tau = taus[k];
        const int mu  = mus[k];
        __syncthreads();                        // prior reads of buf complete

        // mask in regs (P3 positions)
        #pragma unroll
        for (int j = 0; j < 16; ++j) {
            const int r = revtid + ((j & 3) << 10) + ((j >> 2) << 8);
            const int f = (r <= 2048) ? r : (NFFT - r);
            const bool keep = (mu == 1) ? (f < tau) : (f >= tau);
            z[j] = keep ? spec[j] : make_float2(0.f, 0.f);
        }
        // stage0: Y-groups, no twiddle
        bf4_inv(z[0],z[1],z[2],z[3]);
        bf4_inv(z[4],z[5],z[6],z[7]);
        bf4_inv(z[8],z[9],z[10],z[11]);
        bf4_inv(z[12],z[13],z[14],z[15]);
        // stage1: X-groups, k1 = 256*jp (constants)
        bf4_inv(z[0],z[4],z[8],z[12]);
        grp_inv(z[1],z[5],z[9],z[13], W1,W2,W3);
        grp_inv(z[2],z[6],z[10],z[14], W2,W4,W6);
        grp_inv(z[3],z[7],z[11],z[15], W3,W6,W9);
        #pragma unroll
        for (int j = 0; j < 16; ++j) buf[pad(16*tid + j)] = z[j];
        __syncthreads();

        #pragma unroll
        for (int j = 0; j < 16; ++j) z[j] = buf[pad(p2b + 16*j)];
        // stage2: Y-groups, k1 = 64r
        {   float2 w1=w64r, w2=cmul(w1,w1), w3=cmul(w2,w1);
            grp_inv(z[0],z[1],z[2],z[3],  w1,w2,w3);
            grp_inv(z[4],z[5],z[6],z[7],  w1,w2,w3);
            grp_inv(z[8],z[9],z[10],z[11],w1,w2,w3);
            grp_inv(z[12],z[13],z[14],z[15],w1,w2,w3);
        }
        // stage3: X-groups, k1 = 16r + 256*jp
        xgrp_inv(z[0],z[4],z[8],z[12], w16r);
        xgrp_inv(z[1],z[5],z[9],z[13], cmul(w16r,W1));
        xgrp_inv(z[2],z[6],z[10],z[14], cmul(w16r,W2));
        xgrp_inv(z[3],z[7],z[11],z[15], cmul(w16r,W3));
        #pragma unroll
        for (int j = 0; j < 16; ++j) buf[pad(p2b + 16*j)] = z[j];
        __syncthreads();

        #pragma unroll
        for (int j = 0; j < 16; ++j) z[j] = buf[pad(tid + 256*j)];
        // stage4: Y-groups, k1 = 4m
        {   float2 w1=w4m, w2=cmul(w1,w1), w3=cmul(w2,w1);
            grp_inv(z[0],z[1],z[2],z[3],  w1,w2,w3);
            grp_inv(z[4],z[5],z[6],z[7],  w1,w2,w3);
            grp_inv(z[8],z[9],z[10],z[11],w1,w2,w3);
            grp_inv(z[12],z[13],z[14],z[15],w1,w2,w3);
        }
        // stage5: X-groups, k1 = m + 256*jp
        xgrp_inv(z[0],z[4],z[8],z[12], wm);
        xgrp_inv(z[1],z[5],z[9],z[13], cmul(wm,W1));
        xgrp_inv(z[2],z[6],z[10],z[14], cmul(wm,W2));
        xgrp_inv(z[3],z[7],z[11],z[15], cmul(wm,W3));

        // store natural order: thread m owns t = m + 256j
        float* ob = out + ((size_t)(k*NB + b) * NFFT) * NC + c0;
        #pragma unroll
        for (int j = 0; j < 16; ++j) {
            const int t = tid + 256*j;
            *reinterpret_cast<float2*>(ob + (size_t)t * NC) = z[j];
        }
    }
}

} // namespace

extern "C" void kernel_launch(void* const* d_in, const int* in_sizes, int n_in,
                              void* d_out, int out_size, void* d_ws, size_t ws_size,
                              hipStream_t stream) {
    (void)in_sizes; (void)n_in; (void)out_size; (void)d_ws; (void)ws_size;
    const float* x  = (const float*)d_in[0];
    const int* taus = (const int*)d_in[1];
    const int* mus  = (const int*)d_in[2];
    float* out      = (float*)d_out;
    dfl_kernel<<<dim3(NB * NC / 2), dim3(NT), 0, stream>>>(x, taus, mus, out);
}